// Round 2
// baseline (380.472 us; speedup 1.0000x reference)
//
#include <hip/hip_runtime.h>

typedef _Float16 half_t;
typedef __attribute__((ext_vector_type(8))) _Float16 half8;
typedef __attribute__((ext_vector_type(4))) _Float16 half4;
typedef __attribute__((ext_vector_type(2))) _Float16 half2_t;
typedef __attribute__((ext_vector_type(4))) float float4_t;

#define BN_EPS 1e-5f

constexpr int Nn = 64, Cc = 64, Tt = 300, Vv = 25, Ss = 3;
constexpr int TB   = 4;              // timesteps per block (300/4 = 75 exact -> no tail)
constexpr int TWN  = TB * Vv;        // 100 = stage-2 N dimension
constexpr int NT   = 7;              // 7 n-tiles of 16 cover 112 >= 100
constexpr int XL_T = 32;             // v-stride (padded 25->32, pads ZERO = free K-pad)
constexpr int XL_C = TB * XL_T + 8;  // 136 halfs per c row (+8 keeps frag reads 2-way-bank = free)
constexpr int XA_S = 72;             // c-stride of xa rows (144 B, 16B-aligned, 2-way banks)
constexpr int XA_R = NT * 16;        // 112 rows

__global__ __launch_bounds__(256, 4)
void gcn_fused(const float* __restrict__ x,   const float* __restrict__ A,
               const float* __restrict__ PA1, const float* __restrict__ PA2,
               const float* __restrict__ Wc,  const float* __restrict__ bc,
               const float* __restrict__ gamma, const float* __restrict__ beta,
               const float* __restrict__ rmean, const float* __restrict__ rvar,
               float* __restrict__ out)
{
    __shared__ __align__(16) half_t Xl[Cc * XL_C];     // 17408 B
    __shared__ __align__(16) half_t xaL[XA_R * XA_S];  // 16128 B
    __shared__ float bnsc[Cc], bnsh[Cc];               // 512 B   -> ~34 KB total, 4 blocks/CU

    const int tid  = threadIdx.x;
    const int lane = tid & 63;
    const int wave = tid >> 6;      // 0..3
    const int col  = lane & 15;     // MFMA n/m lane index
    const int quad = lane >> 4;     // 0..3

    const int tb = blockIdx.x;      // 0..74
    const int n  = blockIdx.y;      // 0..63
    const int t0 = tb * TB;

    // ---- BN scale/shift with Sum_s bc[s] folded in ----
    if (tid < Cc) {
        float sc   = gamma[tid] * rsqrtf(rvar[tid] + BN_EPS);
        float bsum = bc[tid] + bc[Cc + tid] + bc[2 * Cc + tid];
        bnsc[tid] = sc;
        bnsh[tid] = beta[tid] - rmean[tid] * sc + bsum * sc;
    }

    // ---- stage x slice into LDS, coalesced dword loads, half2 packed writes ----
    // domain: c (64) x t (4) x v0 (16 half2 slots covering v=0..31, pads zero)
    {
        const float* xb = x + (size_t)n * Cc * Tt * Vv + t0 * Vv;
        #pragma unroll
        for (int i = 0; i < 16; ++i) {
            int e = tid + i * 256;               // 4096 slots exact
            int c = e >> 6, r = e & 63, t = r >> 4, v0 = (r & 15) * 2;
            const float* p = xb + c * (Tt * Vv) + t * Vv + v0;
            float f0 = (v0     < Vv) ? p[0] : 0.f;
            float f1 = (v0 + 1 < Vv) ? p[1] : 0.f;
            half2_t hh = { (half_t)f0, (half_t)f1 };
            *(half2_t*)&Xl[c * XL_C + t * XL_T + v0] = hh;   // 4B aligned
        }
    }

    // ---- zero the xa tail rows once (rows 100..111 feed discarded MFMA columns) ----
    for (int e = tid; e < (XA_R - TWN) * XA_S; e += 256)
        xaL[TWN * XA_S + e] = (half_t)0.f;

    // ---- Wc A-fragments (this wave's o-tile) in registers ----
    half8 wf[Ss][2];
    {
        int o = wave * 16 + col;                 // A-frag: m = lane&15
        #pragma unroll
        for (int s = 0; s < Ss; ++s)
            #pragma unroll
            for (int ks = 0; ks < 2; ++ks) {
                const float* p = Wc + (s * Cc + o) * Cc + ks * 32 + quad * 8; // k = quad*8+j
                half8 h;
                #pragma unroll
                for (int j = 0; j < 8; ++j) h[j] = (half_t)p[j];
                wf[s][ks] = h;
            }
    }

    // ---- Ae B-fragments in registers: B[k=v][n=w], k = quad*8+j, n = col ----
    half8 ab[Ss][2];
    #pragma unroll
    for (int s = 0; s < Ss; ++s)
        #pragma unroll
        for (int wt = 0; wt < 2; ++wt) {
            int w = wt * 16 + col;
            half8 h;
            #pragma unroll
            for (int j = 0; j < 8; ++j) {
                int v = quad * 8 + j;
                float val = 0.f;
                if (v < Vv && w < Vv) {
                    int ai = (s * Vv + v) * Vv + w;
                    val = A[ai] * PA1[ai] + PA2[ai];
                }
                h[j] = (half_t)val;
            }
            ab[s][wt] = h;
        }

    __syncthreads();

    const float4_t zero4 = {0.f, 0.f, 0.f, 0.f};
    float4_t yacc[NT];
    #pragma unroll
    for (int i = 0; i < NT; ++i) yacc[i] = zero4;

    for (int s = 0; s < Ss; ++s) {
        // ---- stage 1: xa[c][(t,w)] = X · Ae[s]; this wave owns t = wave ----
        {
            const int t = wave;
            #pragma unroll
            for (int ct = 0; ct < 4; ++ct) {
                // A-frag: m = c = ct*16+col, k = v = quad*8+j (v-pads zero in Xl)
                half8 af = *(const half8*)&Xl[(ct * 16 + col) * XL_C + t * XL_T + quad * 8];
                #pragma unroll
                for (int wt = 0; wt < 2; ++wt) {
                    float4_t r = __builtin_amdgcn_mfma_f32_16x16x32_f16(af, ab[s][wt], zero4, 0, 0, 0);
                    int w = wt * 16 + col;           // C/D: col = lane&15
                    if (w < Vv) {
                        half4 h;
                        #pragma unroll
                        for (int i = 0; i < 4; ++i) h[i] = (half_t)r[i];  // rows quad*4+i = c
                        *(half4*)&xaL[(t * Vv + w) * XA_S + ct * 16 + quad * 4] = h;
                    }
                }
            }
        }
        __syncthreads();

        // ---- stage 2: y[o][(t,w)] += Wc[s] · xa  (M=64 over waves, N=100, K=64) ----
        #pragma unroll
        for (int nt = 0; nt < NT; ++nt) {
            int tw = nt * 16 + col;                  // B-frag: n = tw
            #pragma unroll
            for (int ks = 0; ks < 2; ++ks) {
                half8 bf = *(const half8*)&xaL[tw * XA_S + ks * 32 + quad * 8]; // k = c
                yacc[nt] = __builtin_amdgcn_mfma_f32_16x16x32_f16(wf[s][ks], bf, yacc[nt], 0, 0, 0);
            }
        }
        if (s < Ss - 1) __syncthreads();   // xaL rewritten next s
    }

    // ---- epilogue: BN + residual (from Xl) + ReLU, coalesced stores ----
    float* ob = out + (size_t)n * Cc * Tt * Vv + t0 * Vv;
    #pragma unroll
    for (int nt = 0; nt < NT; ++nt) {
        int tw = nt * 16 + col;
        if (tw < TWN) {
            int t = tw / Vv;            // compiler -> magic mul
            int w = tw - t * Vv;
            #pragma unroll
            for (int i = 0; i < 4; ++i) {
                int o = wave * 16 + quad * 4 + i;
                float val = yacc[nt][i] * bnsc[o] + bnsh[o];
                val += (float)Xl[o * XL_C + t * XL_T + w];   // residual
                ob[o * Tt * Vv + tw] = fmaxf(val, 0.f);      // contiguous in tw
            }
        }
    }
}

extern "C" void kernel_launch(void* const* d_in, const int* in_sizes, int n_in,
                              void* d_out, int out_size, void* d_ws, size_t ws_size,
                              hipStream_t stream) {
    const float* x     = (const float*)d_in[0];
    const float* A     = (const float*)d_in[1];
    const float* PA1   = (const float*)d_in[2];
    const float* PA2   = (const float*)d_in[3];
    const float* Wc    = (const float*)d_in[4];
    const float* bc    = (const float*)d_in[5];
    const float* gamma = (const float*)d_in[6];
    const float* beta  = (const float*)d_in[7];
    const float* rmean = (const float*)d_in[8];
    const float* rvar  = (const float*)d_in[9];
    float* out = (float*)d_out;

    dim3 grid(Tt / TB, Nn);   // (75, 64)
    gcn_fused<<<grid, 256, 0, stream>>>(x, A, PA1, PA2, Wc, bc, gamma, beta, rmean, rvar, out);
}